// Round 20
// baseline (305.806 us; speedup 1.0000x reference)
//
#include <hip/hip_runtime.h>
#include <hip/hip_bf16.h>

// Problem constants (fixed by the reference)
#define BB 8
#define CC 512
#define TT 4096
#define HH 8
#define DH 64
#define EPS 1e-6f

#define NROWS (BB * TT)          // 32768 flat (b,t) rows

using bf16x8 = __attribute__((ext_vector_type(8))) short;
using s16x4  = __attribute__((ext_vector_type(4))) short;
using f32x4  = __attribute__((ext_vector_type(4))) float;

__device__ __forceinline__ short f2b(float f) {
  __hip_bfloat16 h = __float2bfloat16(f);
  return *reinterpret_cast<short*>(&h);
}
__device__ __forceinline__ float b2f(short s) {
  unsigned u = ((unsigned)(unsigned short)s) << 16;
  return __uint_as_float(u);
}

// async global->LDS 16B copy (dest must be wave-uniform base + lane*16)
__device__ __forceinline__ void gld16(short* lds_dst, const short* gsrc) {
  __builtin_amdgcn_global_load_lds(
      (const __attribute__((address_space(1))) unsigned int*)gsrc,
      (__attribute__((address_space(3))) unsigned int*)lds_dst, 16, 0, 0);
}

// 4 weights fp32 [o][c] -> bf16 [o][c], one launch
__global__ __launch_bounds__(256) void conv_w4(const float* __restrict__ s0, const float* __restrict__ s1,
                                               const float* __restrict__ s2, const float* __restrict__ s3,
                                               short* __restrict__ d0, short* __restrict__ d1,
                                               short* __restrict__ d2, short* __restrict__ d3)
{
  const float* src; short* dst;
  switch (blockIdx.y) {
    case 0: src = s0; dst = d0; break;
    case 1: src = s1; dst = d1; break;
    case 2: src = s2; dst = d2; break;
    default: src = s3; dst = d3; break;
  }
  int i8 = (blockIdx.x * 256 + threadIdx.x) * 8;
  float4 a = *(const float4*)(src + i8);
  float4 b = *(const float4*)(src + i8 + 4);
  bf16x8 h = { f2b(a.x), f2b(a.y), f2b(a.z), f2b(a.w),
               f2b(b.x), f2b(b.y), f2b(b.z), f2b(b.w) };
  *(bf16x8*)(dst + i8) = h;
}

// ---------------------------------------------------------------------------
// transpose+convert (r10 best-measured), QUERIES ONLY: fp32 [b][c][t] ->
// bf16 [b][t][c]. grid (T/256, C/64, B).
// ---------------------------------------------------------------------------
#define TSTR 120
__device__ __forceinline__ int tadr(int c, int t) {
  return c * TSTR + ((c >> 3) & 7) * 8 + t;
}

__global__ __launch_bounds__(256) void transpose_cvt1(const float* __restrict__ X,
                                                      short* __restrict__ Xt)
{
  __shared__ short tile[2][64 * TSTR];
  const int t0 = blockIdx.x * 256, c0 = blockIdx.y * 64, b = blockIdx.z;
  const int tid = threadIdx.x;
  const int cl = tid >> 4, t4 = (tid & 15) * 4;       // phase A coords
  const int T2 = (tid >> 3) * 2, ci = (tid & 7) * 8;  // phase B coords

  float4 r[4];
  #pragma unroll
  for (int it = 0; it < 4; ++it)
    r[it] = *(const float4*)(X + ((size_t)b * CC + c0 + it * 16 + cl) * TT + t0 + t4);

  for (int s = 0; s < 4; ++s) {
    const int cur = s & 1;
    #pragma unroll
    for (int it = 0; it < 4; ++it) {
      s16x4 h = { f2b(r[it].x), f2b(r[it].y), f2b(r[it].z), f2b(r[it].w) };
      *(s16x4*)&tile[cur][tadr(it * 16 + cl, t4)] = h;
    }
    if (s < 3) {
      #pragma unroll
      for (int it = 0; it < 4; ++it)
        r[it] = *(const float4*)(X + ((size_t)b * CC + c0 + it * 16 + cl) * TT
                                 + t0 + (s + 1) * 64 + t4);
    }
    __syncthreads();
    unsigned u[8];
    #pragma unroll
    for (int i = 0; i < 8; ++i)
      u[i] = *(const unsigned*)&tile[cur][tadr(ci + i, T2)];
    short lo[8], hi[8];
    #pragma unroll
    for (int i = 0; i < 8; ++i) {
      lo[i] = (short)(u[i] & 0xffffu);
      hi[i] = (short)(u[i] >> 16);
    }
    short* dst0 = Xt + ((size_t)b * TT + t0 + s * 64 + T2) * CC + c0 + ci;
    *(bf16x8*)dst0 = *(bf16x8*)&lo[0];
    *(bf16x8*)(dst0 + CC) = *(bf16x8*)&hi[0];
  }
}

// ---------------------------------------------------------------------------
// bf16-A GEMM (r10 measured-best): Y[m][o] = sum_c A[m][c]*W[o][c]+bias.
// 128x128, BK=32, double-buffered LDS, both-sides XOR swizzle, gld16 staging.
// ---------------------------------------------------------------------------
__global__ __launch_bounds__(256) void gemm_tc(const short* __restrict__ A,
                                               const short* __restrict__ W,
                                               const float* __restrict__ bias,
                                               short* __restrict__ Y)
{
  __shared__ short As[2 * 4096];
  __shared__ short Bs[2 * 4096];
  const int tid = threadIdx.x;
  int x = blockIdx.x;
  int wg = (x & 7) * 128 + (x >> 3);       // XCD-chunked
  const int m0 = (wg >> 2) * 128;
  const int o0 = (wg & 3) * 128;

  const int wid = tid >> 6, lane = tid & 63;
  const int wr = (wid >> 1) * 64, wc = (wid & 1) * 64;
  const int lr = lane & 15, g = lane >> 4;
  const int swz8 = (g ^ ((lr >> 1) & 3)) * 8;
  const int srow0 = tid >> 2;
  const int scol  = ((tid & 3) ^ ((tid >> 3) & 3)) * 8;

  f32x4 acc[4][4] = {};

  #pragma unroll
  for (int it = 0; it < 2; ++it) {
    int row = it * 64 + srow0;
    gld16(&As[it * 2048 + tid * 8], A + (size_t)(m0 + row) * CC + scol);
    gld16(&Bs[it * 2048 + tid * 8], W + (size_t)(o0 + row) * CC + scol);
  }
  __syncthreads();

  for (int step = 0; step < 16; ++step) {
    const int cur = step & 1;
    if (step < 15) {
      const int k0 = (step + 1) * 32;
      #pragma unroll
      for (int it = 0; it < 2; ++it) {
        int row = it * 64 + srow0;
        gld16(&As[(cur ^ 1) * 4096 + it * 2048 + tid * 8], A + (size_t)(m0 + row) * CC + k0 + scol);
        gld16(&Bs[(cur ^ 1) * 4096 + it * 2048 + tid * 8], W + (size_t)(o0 + row) * CC + k0 + scol);
      }
    }
    bf16x8 af[4], bf[4];
    #pragma unroll
    for (int m = 0; m < 4; ++m) af[m] = *(const bf16x8*)&As[cur * 4096 + (wr + m * 16 + lr) * 32 + swz8];
    #pragma unroll
    for (int n = 0; n < 4; ++n) bf[n] = *(const bf16x8*)&Bs[cur * 4096 + (wc + n * 16 + lr) * 32 + swz8];
    #pragma unroll
    for (int m = 0; m < 4; ++m)
      #pragma unroll
      for (int n = 0; n < 4; ++n)
        acc[m][n] = __builtin_amdgcn_mfma_f32_16x16x32_bf16(af[m], bf[n], acc[m][n], 0, 0, 0);
    __syncthreads();
  }

  const int lq4 = (lane >> 4) * 4;
  #pragma unroll
  for (int m = 0; m < 4; ++m)
    #pragma unroll
    for (int r = 0; r < 4; ++r) {
      size_t row = (size_t)(m0 + wr + m * 16 + lq4 + r) * CC;
      #pragma unroll
      for (int n = 0; n < 4; ++n) {
        int o = o0 + wc + n * 16 + lr;
        Y[row + o] = f2b(acc[m][n][r] + bias[o]);
      }
    }
}

// ---------------------------------------------------------------------------
// fp32-A direct GEMM v4: 3-deep A register pipeline (counted latency, no
// vmcnt(0) in main loop). rc=A(s+1), rc2=A(s+2), issue A(s+3) each step.
// ---------------------------------------------------------------------------
#define AST 40
__device__ __forceinline__ int aadr(int m, int c) {
  return m * AST + ((m >> 2) & 7) * 8 + c;
}

__global__ __launch_bounds__(256) void gemm_direct2(
    const float* __restrict__ X0, const float* __restrict__ X1,
    const short* __restrict__ W0, const short* __restrict__ W1,
    const float* __restrict__ b0, const float* __restrict__ b1,
    short* __restrict__ Y0, short* __restrict__ Y1)
{
  __shared__ short Am[2][5184];
  __shared__ short Ws[2][4096];
  const float* Xf = blockIdx.y == 0 ? X0 : X1;
  const short* W  = blockIdx.y == 0 ? W0 : W1;
  const float* bias = blockIdx.y == 0 ? b0 : b1;
  short* Y        = blockIdx.y == 0 ? Y0 : Y1;

  const int tid = threadIdx.x;
  int x = blockIdx.x;
  int wg = (x & 7) * 128 + (x >> 3);       // XCD-chunked
  const int m0 = (wg >> 2) * 128;
  const int o0 = (wg & 3) * 128;
  const int b = m0 >> 12, t0 = m0 & 4095;  // 128-row tiles never straddle b
  const float* Xb = Xf + (size_t)b * CC * TT + t0;

  const int wid = tid >> 6, lane = tid & 63;
  const int wr = (wid >> 1) * 64, wc = (wid & 1) * 64;
  const int lr = lane & 15, g = lane >> 4;
  const int lk8 = g * 8;
  const int swz8 = (g ^ ((lr >> 1) & 3)) * 8;            // W read swizzle
  const int srow0 = tid >> 2;
  const int scol  = ((tid & 3) ^ ((tid >> 3) & 3)) * 8;  // W source swizzle

  const int t4 = (tid & 31) * 4;           // A staging coords
  const int c4 = (tid >> 5) * 4;

  f32x4 acc[4][4] = {};

  // prologue: A(0) -> Am[0]; W(0) gld16; A(1) -> rc; A(2) -> rc2
  {
    float4 r0[4];
    #pragma unroll
    for (int j = 0; j < 4; ++j)
      r0[j] = *(const float4*)(Xb + (size_t)(c4 + j) * TT + t4);
    #pragma unroll
    for (int jt = 0; jt < 4; ++jt) {
      int m = t4 + jt;
      s16x4 h = { f2b(r0[0][jt]), f2b(r0[1][jt]), f2b(r0[2][jt]), f2b(r0[3][jt]) };
      *(s16x4*)&Am[0][aadr(m, c4)] = h;
    }
  }
  #pragma unroll
  for (int it = 0; it < 2; ++it)
    gld16(&Ws[0][it * 2048 + tid * 8], W + (size_t)(o0 + it * 64 + srow0) * CC + scol);
  __builtin_amdgcn_sched_barrier(0);       // pin W(0) issue before A(1)/A(2)
  float4 rc[4], rc2[4];
  #pragma unroll
  for (int j = 0; j < 4; ++j)
    rc[j] = *(const float4*)(Xb + (size_t)(32 + c4 + j) * TT + t4);
  #pragma unroll
  for (int j = 0; j < 4; ++j)
    rc2[j] = *(const float4*)(Xb + (size_t)(64 + c4 + j) * TT + t4);

  for (int step = 0; step < 16; ++step) {
    const int cur = step & 1;
    // (1) issue W(s+1) gld16 FIRST (older than this step's A loads)
    if (step < 15) {
      const int k0 = (step + 1) * 32;
      #pragma unroll
      for (int it = 0; it < 2; ++it)
        gld16(&Ws[cur ^ 1][it * 2048 + tid * 8], W + (size_t)(o0 + it * 64 + srow0) * CC + k0 + scol);
    }
    __builtin_amdgcn_sched_barrier(0);
    // (2) issue A(s+3) register loads (3 steps of slack)
    float4 rn[4];
    if (step < 13) {
      const int k3 = (step + 3) * 32;
      #pragma unroll
      for (int j = 0; j < 4; ++j)
        rn[j] = *(const float4*)(Xb + (size_t)(k3 + c4 + j) * TT + t4);
    }
    // (3) convert A(s+1) (issued 3 steps ago) -> Am[cur^1]; data-dep wait
    //     on rc retires the older W(s) gld16s too (in-order vmcnt)
    if (step < 15) {
      #pragma unroll
      for (int jt = 0; jt < 4; ++jt) {
        int m = t4 + jt;
        s16x4 h = { f2b(rc[0][jt]), f2b(rc[1][jt]), f2b(rc[2][jt]), f2b(rc[3][jt]) };
        *(s16x4*)&Am[cur ^ 1][aadr(m, c4)] = h;
      }
    } else {
      asm volatile("s_waitcnt vmcnt(0)" ::: "memory");   // tail: W(15) landed
    }
    // (4) LDS writes visible + barrier (vmcnt NOT drained — prefetch lives)
    asm volatile("s_waitcnt lgkmcnt(0)" ::: "memory");
    __builtin_amdgcn_s_barrier();
    __builtin_amdgcn_sched_barrier(0);

    // (5) MFMA on current buffers
    bf16x8 af[4], bf[4];
    #pragma unroll
    for (int m = 0; m < 4; ++m) af[m] = *(const bf16x8*)&Am[cur][aadr(wr + m * 16 + lr, lk8)];
    #pragma unroll
    for (int n = 0; n < 4; ++n) bf[n] = *(const bf16x8*)&Ws[cur][(wc + n * 16 + lr) * 32 + swz8];
    #pragma unroll
    for (int m = 0; m < 4; ++m)
      #pragma unroll
      for (int n = 0; n < 4; ++n)
        acc[m][n] = __builtin_amdgcn_mfma_f32_16x16x32_bf16(af[m], bf[n], acc[m][n], 0, 0, 0);

    // (6) buffer-reuse barrier (LDS reads complete before next-step writes)
    __builtin_amdgcn_sched_barrier(0);
    __builtin_amdgcn_s_barrier();
    __builtin_amdgcn_sched_barrier(0);

    // (7) shift the A pipeline
    if (step < 13) {
      #pragma unroll
      for (int j = 0; j < 4; ++j) { rc[j] = rc2[j]; rc2[j] = rn[j]; }
    } else if (step == 13) {
      #pragma unroll
      for (int j = 0; j < 4; ++j) rc[j] = rc2[j];
    }
  }

  const int lq4 = (lane >> 4) * 4;
  #pragma unroll
  for (int m = 0; m < 4; ++m)
    #pragma unroll
    for (int r = 0; r < 4; ++r) {
      size_t row = (size_t)(m0 + wr + m * 16 + lq4 + r) * CC;
      #pragma unroll
      for (int n = 0; n < 4; ++n) {
        int o = o0 + wc + n * 16 + lr;
        Y[row + o] = f2b(acc[m][n][r] + bias[o]);
      }
    }
}

// ---------------------------------------------------------------------------
// Row feature kernel on [row][512] bf16, wave per row, in-place; all 3
// tensors in one launch (blockIdx.y = mode).
// mode 0=Q (rms->elu+1->per-head softmax->*8^-0.5)
//      1=K (rms->elu+1->EXP, masked rows -> 0)   [normalization deferred]
//      2=V (rms->elu+1->/64)
// ---------------------------------------------------------------------------
__global__ __launch_bounds__(256) void feat_all(short* __restrict__ qf, short* __restrict__ kf,
                                                short* __restrict__ vf,
                                                const float* __restrict__ gq,
                                                const float* __restrict__ gk,
                                                const float* __restrict__ gv,
                                                const unsigned char* __restrict__ mask)
{
  const int mode = blockIdx.y;
  short* buf = mode == 0 ? qf : (mode == 1 ? kf : vf);
  const float* g = mode == 0 ? gq : (mode == 1 ? gk : gv);
  const int row = blockIdx.x * 4 + (threadIdx.x >> 6);
  const int lane = threadIdx.x & 63;
  short* p = buf + (size_t)row * CC + lane * 8;
  if (mode == 1 && mask[row]) {            // whole (b,t) row masked -> exp = 0
    bf16x8 z = { 0,0,0,0,0,0,0,0 };
    *(bf16x8*)p = z;
    return;
  }
  bf16x8 v = *(const bf16x8*)p;
  float x[8], ss = 0.f;
  #pragma unroll
  for (int j = 0; j < 8; ++j) { x[j] = b2f(v[j]); ss += x[j] * x[j]; }
  #pragma unroll
  for (int off = 32; off; off >>= 1) ss += __shfl_xor(ss, off);
  float rn = rsqrtf(ss * (1.0f / CC) + EPS);
  float4 g0 = *(const float4*)(g + lane * 8);
  float4 g1 = *(const float4*)(g + lane * 8 + 4);
  float gv8[8] = { g0.x, g0.y, g0.z, g0.w, g1.x, g1.y, g1.z, g1.w };
  float f[8];
  #pragma unroll
  for (int j = 0; j < 8; ++j) {
    float t = x[j] * rn * gv8[j];
    f[j] = t > 0.f ? t + 1.f : __expf(t);
  }
  bf16x8 o;
  if (mode == 1) {
    #pragma unroll
    for (int j = 0; j < 8; ++j) o[j] = f2b(__expf(f[j]));   // unnormalized exp
  } else if (mode == 2) {
    #pragma unroll
    for (int j = 0; j < 8; ++j) o[j] = f2b(f[j] * (1.0f / DH));
  } else {  // Q: softmax over head (64 c = 8 lanes), no max-sub (f <= ~24)
    float ls = 0.f;
    #pragma unroll
    for (int j = 0; j < 8; ++j) { f[j] = __expf(f[j]); ls += f[j]; }
    ls += __shfl_xor(ls, 1); ls += __shfl_xor(ls, 2); ls += __shfl_xor(ls, 4);
    float sc = 0.35355339059327373f / ls;     // 8^-0.5 / sum
    #pragma unroll
    for (int j = 0; j < 8; ++j) o[j] = f2b(f[j] * sc);
  }
  *(bf16x8*)p = o;
}

// column-sum of kf_exp over t: S[b][c] = sum_t kfe[b][t][c]
__global__ __launch_bounds__(256) void ksm_sum(const short* __restrict__ kfe,
                                               float* __restrict__ S)
{
  const int b = blockIdx.y, tch = blockIdx.x;
  const int c2 = threadIdx.x * 2;
  float s0 = 0.f, s1 = 0.f;
  for (int t = 0; t < 128; ++t) {
    unsigned u = *(const unsigned*)&kfe[((size_t)b * TT + tch * 128 + t) * CC + c2];
    s0 += __uint_as_float(u << 16);
    s1 += __uint_as_float(u & 0xffff0000u);
  }
  atomicAdd(&S[b * CC + c2], s0);
  atomicAdd(&S[b * CC + c2 + 1], s1);
}

// ---------------------------------------------------------------------------
// ctx partials from t-major kfe/vf: P[tc][bh][q][v] = sum_t kfe[t][q]*vf[t][v]
// ---------------------------------------------------------------------------
__global__ __launch_bounds__(256) void ctx_t(const short* __restrict__ kf,
                                             const short* __restrict__ vf,
                                             float* __restrict__ P)
{
  __shared__ short Ks[64 * 64];
  __shared__ short Vs[64 * 64];
  const int tc = blockIdx.x, bh = blockIdx.y;
  const int b = bh >> 3, h = bh & 7;
  const int tid = threadIdx.x, wid = tid >> 6, lane = tid & 63;
  const int lr = lane & 15, lg = lane >> 4;
  f32x4 acc[4] = {};

  for (int ts = 0; ts < 8; ++ts) {
    #pragma unroll
    for (int i = 0; i < 2; ++i) {
      int n = i * 256 + tid;
      int t = n >> 3, ch = (n & 7) * 8;
      size_t src = ((size_t)b * TT + tc * 512 + ts * 64 + t) * CC + h * DH + ch;
      gld16(Ks + n * 8, kf + src);
      gld16(Vs + n * 8, vf + src);
    }
    __syncthreads();
    #pragma unroll
    for (int kk = 0; kk < 64; kk += 32) {
      short a[8];
      #pragma unroll
      for (int j = 0; j < 8; ++j)
        a[j] = Ks[(kk + lg * 8 + j) * 64 + wid * 16 + lr];
      bf16x8 af = *(const bf16x8*)&a[0];
      #pragma unroll
      for (int n = 0; n < 4; ++n) {
        short bv[8];
        #pragma unroll
        for (int j = 0; j < 8; ++j)
          bv[j] = Vs[(kk + lg * 8 + j) * 64 + n * 16 + lr];
        acc[n] = __builtin_amdgcn_mfma_f32_16x16x32_bf16(af, *(const bf16x8*)&bv[0],
                                                         acc[n], 0, 0, 0);
      }
    }
    __syncthreads();
  }
  float* pp = P + ((size_t)tc * 64 + bh) * (DH * DH);
  const int lq4 = lg * 4;
  #pragma unroll
  for (int n = 0; n < 4; ++n)
    #pragma unroll
    for (int r = 0; r < 4; ++r)
      pp[(wid * 16 + lq4 + r) * DH + n * 16 + lr] = acc[n][r];
}

// reduce chunk partials, apply 1/S (deferred k-softmax norm), emit CT[bh][v][q]
__global__ __launch_bounds__(256) void ctx_reduce(const float* __restrict__ P,
                                                  const float* __restrict__ S,
                                                  short* __restrict__ CT)
{
  int i = blockIdx.x * 256 + threadIdx.x;    // (bh, q, v), v fastest
  float s = 0.f;
  #pragma unroll
  for (int c = 0; c < 8; ++c) s += P[(size_t)c * 64 * DH * DH + i];
  int bh = i >> 12, rem = i & 4095, q = rem >> 6, v = rem & 63;
  int b = bh >> 3, h = bh & 7;
  float inv = 1.f / S[b * CC + h * DH + q];
  CT[((size_t)bh << 12) + v * 64 + q] = f2b(s * inv);
}

// ---------------------------------------------------------------------------
// attn: ao[row][h*64+v] = sum_q qf[row][h*64+q] * CT[bh][v][q]
// ---------------------------------------------------------------------------
__global__ __launch_bounds__(256) void attn_t(const short* __restrict__ qf,
                                              const short* __restrict__ CT,
                                              short* __restrict__ ao)
{
  __shared__ short As[128 * 72];
  __shared__ short Cs[64 * 72];
  const int m0 = blockIdx.x * 128, h = blockIdx.y;
  const int tid = threadIdx.x, wid = tid >> 6, lane = tid & 63;
  const int lr = lane & 15, lk8 = (lane >> 4) * 8;

  #pragma unroll
  for (int i = 0; i < 4; ++i) {
    int n = i * 256 + tid;
    int r = n >> 3, ch = (n & 7) * 8;
    *(bf16x8*)&As[r * 72 + ch] =
        *(const bf16x8*)(qf + (size_t)(m0 + r) * CC + h * DH + ch);
  }
  {
    const int bh0 = (m0 / TT) * 8 + h;
    #pragma unroll
    for (int i = 0; i < 2; ++i) {
      int n = i * 256 + tid;
      int v = n >> 3, ch = (n & 7) * 8;
      *(bf16x8*)&Cs[v * 72 + ch] = *(const bf16x8*)(CT + ((size_t)bh0 << 12) + v * 64 + ch);
    }
  }
  __syncthreads();

  const int wr = wid * 32;
  f32x4 acc[2][4] = {};
  #pragma unroll
  for (int kk = 0; kk < 64; kk += 32) {
    bf16x8 af[2], cf[4];
    #pragma unroll
    for (int m = 0; m < 2; ++m) af[m] = *(const bf16x8*)&As[(wr + m * 16 + lr) * 72 + kk + lk8];
    #pragma unroll
    for (int n = 0; n < 4; ++n) cf[n] = *(const bf16x8*)&Cs[(n * 16 + lr) * 72 + kk + lk8];
    #pragma unroll
    for (int m = 0; m < 2; ++m)
      #pragma unroll
      for (int n = 0; n < 4; ++n)
        acc[m][n] = __builtin_amdgcn_mfma_f32_16x16x32_bf16(af[m], cf[n], acc[m][n], 0, 0, 0);
  }
  const int lq4 = (lane >> 4) * 4;
  #pragma unroll
  for (int m = 0; m < 2; ++m)
    #pragma unroll
    for (int r = 0; r < 4; ++r) {
      size_t row = (size_t)(m0 + wr + m * 16 + lq4 + r) * CC + h * DH;
      #pragma unroll
      for (int n = 0; n < 4; ++n)
        ao[row + n * 16 + lr] = f2b(acc[m][n][r]);
    }
}

// ---------------------------------------------------------------------------
// fused final v3 (r19 measured-best): 128-t x 512-c tile, 512 thr, 139 KB LDS.
// ---------------------------------------------------------------------------
#define ZSTR 136
__device__ __forceinline__ int zadr(int c, int t) {
  return c * ZSTR + ((c >> 7) & 3) * 8 + t;
}

__global__ __launch_bounds__(512) void final_fused(const short* __restrict__ pj,
                                                   const short* __restrict__ qt,
                                                   const float* __restrict__ g,
                                                   float* __restrict__ out)
{
  __shared__ short z[512 * ZSTR + 32];     // 139,328 B
  __shared__ float rmss[128];
  const int t0 = blockIdx.x * 128, b = blockIdx.y;
  const int tid = threadIdx.x;

  // pass 1: thread = (t = tid>>2 in 0..127, cb = (tid&3)*128)
  {
    const int t = tid >> 2, cb = (tid & 3) * 128;
    const size_t row = ((size_t)b * TT + t0 + t) * CC + cb;
    float ss = 0.f;
    #pragma unroll
    for (int j = 0; j < 16; ++j) {
      bf16x8 a = *(const bf16x8*)(pj + row + j * 8);
      bf16x8 q = *(const bf16x8*)(qt + row + j * 8);
      #pragma unroll
      for (int e = 0; e < 8; ++e) {
        float zf = b2f(a[e]) + b2f(q[e]);
        ss += zf * zf;
        z[zadr(cb + j * 8 + e, t)] = f2b(zf);
      }
    }
    ss += __shfl_xor(ss, 1);
    ss += __shfl_xor(ss, 2);
    if ((tid & 3) == 0) rmss[t] = rsqrtf(ss * (1.0f / CC) + EPS);
  }
  __syncthreads();

  // pass 2: 4 c-passes; thread = (c = p*128 + tid>>2, tcs = (tid&3)*32)
  const int ci = tid >> 2, tcs = (tid & 3) * 32;
  #pragma unroll 1
  for (int p = 0; p < 4; ++p) {
    const int cc = p * 128 + ci;
    const float gc = g[cc];
    float* dst = out + ((size_t)b * CC + cc) * TT + t0 + tcs;
    #pragma unroll
    for (int q8 = 0; q8 < 4; ++q8) {
      bf16x8 zv = *(const bf16x8*)&z[zadr(cc, tcs + q8 * 8)];
      float4 o0 = { b2f(zv[0]) * rmss[tcs+q8*8+0] * gc, b2f(zv[1]) * rmss[tcs+q8*8+1] * gc,
                    b2f(zv[2]) * rmss[tcs+q8*8+2] * gc, b2f(zv[3]) * rmss[tcs+q8*8+3] * gc };
      float4 o1 = { b2f(zv[4]) * rmss[tcs+q8*8+4] * gc, b2f(zv[5]) * rmss[tcs+q8*8+5] * gc,
                    b2f(zv[6]) * rmss[tcs+q8*8+6] * gc, b2f(zv[7]) * rmss[tcs+q8*8+7] * gc };
      *(float4*)(dst + q8 * 8) = o0;
      *(float4*)(dst + q8 * 8 + 4) = o1;
    }
  }
}

// ---------------------------------------------------------------------------
extern "C" void kernel_launch(void* const* d_in, const int* in_sizes, int n_in,
                              void* d_out, int out_size, void* d_ws, size_t ws_size,
                              hipStream_t stream) {
  (void)in_sizes; (void)n_in; (void)out_size; (void)ws_size;
  const float* queries = (const float*)d_in[0];
  const float* keys    = (const float*)d_in[1];
  const float* values  = (const float*)d_in[2];
  const unsigned char* mask = (const unsigned char*)d_in[3];
  const float* Wq = (const float*)d_in[4];
  const float* bq = (const float*)d_in[5];
  const float* gq = (const float*)d_in[6];
  const float* Wk = (const float*)d_in[7];
  const float* bk = (const float*)d_in[8];
  const float* gk = (const float*)d_in[9];
  const float* Wv = (const float*)d_in[10];
  const float* bv = (const float*)d_in[11];
  const float* gv = (const float*)d_in[12];
  const float* Wp = (const float*)d_in[13];
  const float* bp = (const float*)d_in[14];
  const float* g_out = (const float*)d_in[15];

  const size_t NCT = (size_t)NROWS * CC;       // 16,777,216 elements
  short* qt = (short*)d_ws;                    // bf16 [row][c] transposed queries
  short* qf = qt + NCT;                        // feature buffers
  short* kf = qf + NCT;
  short* vf = kf + NCT;
  short* ao = vf + NCT;                        // attention output
  short* pj = ao + NCT;                        // projection output
  float* ctxP = (float*)(pj + NCT);            // 8 x 64 x 4096 fp32
  short* CT  = (short*)(ctxP + (size_t)8 * 64 * DH * DH);   // [bh][v][q] bf16
  short* wqb = CT + (size_t)64 * DH * DH;
  short* wkb = wqb + (size_t)CC * CC;
  short* wvb = wkb + (size_t)CC * CC;
  short* wpb = wvb + (size_t)CC * CC;
  float* S   = (float*)(wpb + (size_t)CC * CC);   // [B][C] softmax sums

  hipMemsetAsync(S, 0, (size_t)BB * CC * sizeof(float), stream);

  conv_w4<<<dim3(CC * CC / 2048, 4), 256, 0, stream>>>(Wq, Wk, Wv, Wp, wqb, wkb, wvb, wpb);

  transpose_cvt1<<<dim3(TT / 256, CC / 64, BB), 256, 0, stream>>>(queries, qt);

  gemm_tc<<<dim3(1024), 256, 0, stream>>>(qt, wqb, bq, qf);

  gemm_direct2<<<dim3(1024, 2), 256, 0, stream>>>(keys, values, wkb, wvb,
                                                  bk, bv, kf, vf);

  feat_all<<<dim3(NROWS / 4, 3), 256, 0, stream>>>(qf, kf, vf, gq, gk, gv, mask);

  ksm_sum<<<dim3(32, BB), 256, 0, stream>>>(kf, S);

  ctx_t<<<dim3(8, BB * HH), 256, 0, stream>>>(kf, vf, ctxP);
  ctx_reduce<<<dim3(64 * DH * DH / 256), 256, 0, stream>>>(ctxP, S, CT);

  attn_t<<<dim3(NROWS / 128, HH), 256, 0, stream>>>(qf, CT, ao);

  gemm_tc<<<dim3(1024), 256, 0, stream>>>(ao, wpb, bp, pj);

  final_fused<<<dim3(TT / 128, BB), 512, 0, stream>>>(pj, qt, g_out, (float*)d_out);
}

// Round 21
// 285.786 us; speedup vs baseline: 1.0701x; 1.0701x over previous
//
#include <hip/hip_runtime.h>
#include <hip/hip_bf16.h>

// Problem constants (fixed by the reference)
#define BB 8
#define CC 512
#define TT 4096
#define HH 8
#define DH 64
#define EPS 1e-6f

#define NROWS (BB * TT)          // 32768 flat (b,t) rows

using bf16x8 = __attribute__((ext_vector_type(8))) short;
using s16x4  = __attribute__((ext_vector_type(4))) short;
using f32x4  = __attribute__((ext_vector_type(4))) float;

__device__ __forceinline__ short f2b(float f) {
  __hip_bfloat16 h = __float2bfloat16(f);
  return *reinterpret_cast<short*>(&h);
}
__device__ __forceinline__ float b2f(short s) {
  unsigned u = ((unsigned)(unsigned short)s) << 16;
  return __uint_as_float(u);
}

// async global->LDS 16B copy (dest must be wave-uniform base + lane*16)
__device__ __forceinline__ void gld16(short* lds_dst, const short* gsrc) {
  __builtin_amdgcn_global_load_lds(
      (const __attribute__((address_space(1))) unsigned int*)gsrc,
      (__attribute__((address_space(3))) unsigned int*)lds_dst, 16, 0, 0);
}

// 4 weights fp32 [o][c] -> bf16 [o][c], one launch
__global__ __launch_bounds__(256) void conv_w4(const float* __restrict__ s0, const float* __restrict__ s1,
                                               const float* __restrict__ s2, const float* __restrict__ s3,
                                               short* __restrict__ d0, short* __restrict__ d1,
                                               short* __restrict__ d2, short* __restrict__ d3)
{
  const float* src; short* dst;
  switch (blockIdx.y) {
    case 0: src = s0; dst = d0; break;
    case 1: src = s1; dst = d1; break;
    case 2: src = s2; dst = d2; break;
    default: src = s3; dst = d3; break;
  }
  int i8 = (blockIdx.x * 256 + threadIdx.x) * 8;
  float4 a = *(const float4*)(src + i8);
  float4 b = *(const float4*)(src + i8 + 4);
  bf16x8 h = { f2b(a.x), f2b(a.y), f2b(a.z), f2b(a.w),
               f2b(b.x), f2b(b.y), f2b(b.z), f2b(b.w) };
  *(bf16x8*)(dst + i8) = h;
}

// ---------------------------------------------------------------------------
// transpose+convert (r10 best-measured), QUERIES ONLY: fp32 [b][c][t] ->
// bf16 [b][t][c]. grid (T/256, C/64, B).
// ---------------------------------------------------------------------------
#define TSTR 120
__device__ __forceinline__ int tadr(int c, int t) {
  return c * TSTR + ((c >> 3) & 7) * 8 + t;
}

__global__ __launch_bounds__(256) void transpose_cvt1(const float* __restrict__ X,
                                                      short* __restrict__ Xt)
{
  __shared__ short tile[2][64 * TSTR];
  const int t0 = blockIdx.x * 256, c0 = blockIdx.y * 64, b = blockIdx.z;
  const int tid = threadIdx.x;
  const int cl = tid >> 4, t4 = (tid & 15) * 4;       // phase A coords
  const int T2 = (tid >> 3) * 2, ci = (tid & 7) * 8;  // phase B coords

  float4 r[4];
  #pragma unroll
  for (int it = 0; it < 4; ++it)
    r[it] = *(const float4*)(X + ((size_t)b * CC + c0 + it * 16 + cl) * TT + t0 + t4);

  for (int s = 0; s < 4; ++s) {
    const int cur = s & 1;
    #pragma unroll
    for (int it = 0; it < 4; ++it) {
      s16x4 h = { f2b(r[it].x), f2b(r[it].y), f2b(r[it].z), f2b(r[it].w) };
      *(s16x4*)&tile[cur][tadr(it * 16 + cl, t4)] = h;
    }
    if (s < 3) {
      #pragma unroll
      for (int it = 0; it < 4; ++it)
        r[it] = *(const float4*)(X + ((size_t)b * CC + c0 + it * 16 + cl) * TT
                                 + t0 + (s + 1) * 64 + t4);
    }
    __syncthreads();
    unsigned u[8];
    #pragma unroll
    for (int i = 0; i < 8; ++i)
      u[i] = *(const unsigned*)&tile[cur][tadr(ci + i, T2)];
    short lo[8], hi[8];
    #pragma unroll
    for (int i = 0; i < 8; ++i) {
      lo[i] = (short)(u[i] & 0xffffu);
      hi[i] = (short)(u[i] >> 16);
    }
    short* dst0 = Xt + ((size_t)b * TT + t0 + s * 64 + T2) * CC + c0 + ci;
    *(bf16x8*)dst0 = *(bf16x8*)&lo[0];
    *(bf16x8*)(dst0 + CC) = *(bf16x8*)&hi[0];
  }
}

// ---------------------------------------------------------------------------
// bf16-A GEMM (r10 measured-best): Y[m][o] = sum_c A[m][c]*W[o][c]+bias.
// 128x128, BK=32, double-buffered LDS, both-sides XOR swizzle, gld16 staging.
// ---------------------------------------------------------------------------
__global__ __launch_bounds__(256) void gemm_tc(const short* __restrict__ A,
                                               const short* __restrict__ W,
                                               const float* __restrict__ bias,
                                               short* __restrict__ Y)
{
  __shared__ short As[2 * 4096];
  __shared__ short Bs[2 * 4096];
  const int tid = threadIdx.x;
  int x = blockIdx.x;
  int wg = (x & 7) * 128 + (x >> 3);       // XCD-chunked
  const int m0 = (wg >> 2) * 128;
  const int o0 = (wg & 3) * 128;

  const int wid = tid >> 6, lane = tid & 63;
  const int wr = (wid >> 1) * 64, wc = (wid & 1) * 64;
  const int lr = lane & 15, g = lane >> 4;
  const int swz8 = (g ^ ((lr >> 1) & 3)) * 8;
  const int srow0 = tid >> 2;
  const int scol  = ((tid & 3) ^ ((tid >> 3) & 3)) * 8;

  f32x4 acc[4][4] = {};

  #pragma unroll
  for (int it = 0; it < 2; ++it) {
    int row = it * 64 + srow0;
    gld16(&As[it * 2048 + tid * 8], A + (size_t)(m0 + row) * CC + scol);
    gld16(&Bs[it * 2048 + tid * 8], W + (size_t)(o0 + row) * CC + scol);
  }
  __syncthreads();

  for (int step = 0; step < 16; ++step) {
    const int cur = step & 1;
    if (step < 15) {
      const int k0 = (step + 1) * 32;
      #pragma unroll
      for (int it = 0; it < 2; ++it) {
        int row = it * 64 + srow0;
        gld16(&As[(cur ^ 1) * 4096 + it * 2048 + tid * 8], A + (size_t)(m0 + row) * CC + k0 + scol);
        gld16(&Bs[(cur ^ 1) * 4096 + it * 2048 + tid * 8], W + (size_t)(o0 + row) * CC + k0 + scol);
      }
    }
    bf16x8 af[4], bf[4];
    #pragma unroll
    for (int m = 0; m < 4; ++m) af[m] = *(const bf16x8*)&As[cur * 4096 + (wr + m * 16 + lr) * 32 + swz8];
    #pragma unroll
    for (int n = 0; n < 4; ++n) bf[n] = *(const bf16x8*)&Bs[cur * 4096 + (wc + n * 16 + lr) * 32 + swz8];
    #pragma unroll
    for (int m = 0; m < 4; ++m)
      #pragma unroll
      for (int n = 0; n < 4; ++n)
        acc[m][n] = __builtin_amdgcn_mfma_f32_16x16x32_bf16(af[m], bf[n], acc[m][n], 0, 0, 0);
    __syncthreads();
  }

  const int lq4 = (lane >> 4) * 4;
  #pragma unroll
  for (int m = 0; m < 4; ++m)
    #pragma unroll
    for (int r = 0; r < 4; ++r) {
      size_t row = (size_t)(m0 + wr + m * 16 + lq4 + r) * CC;
      #pragma unroll
      for (int n = 0; n < 4; ++n) {
        int o = o0 + wc + n * 16 + lr;
        Y[row + o] = f2b(acc[m][n][r] + bias[o]);
      }
    }
}

// ---------------------------------------------------------------------------
// fp32-A direct GEMM v3 (r19 measured-best): counted-latency pipeline, NO
// vmcnt(0) drains in main loop. Per step: (1) gld16 W(s+1), (2) A(s+2)
// register loads, (3) convert A(s+1)->Am[cur^1] (data-dep vmcnt retires the
// older W(s) gld16s too), (4) lgkm drain + raw barrier, (5) MFMA, (6) raw
// barrier. grid (1024, 2): keys / values.
// ---------------------------------------------------------------------------
#define AST 40
__device__ __forceinline__ int aadr(int m, int c) {
  return m * AST + ((m >> 2) & 7) * 8 + c;
}

__global__ __launch_bounds__(256) void gemm_direct2(
    const float* __restrict__ X0, const float* __restrict__ X1,
    const short* __restrict__ W0, const short* __restrict__ W1,
    const float* __restrict__ b0, const float* __restrict__ b1,
    short* __restrict__ Y0, short* __restrict__ Y1)
{
  __shared__ short Am[2][5184];
  __shared__ short Ws[2][4096];
  const float* Xf = blockIdx.y == 0 ? X0 : X1;
  const short* W  = blockIdx.y == 0 ? W0 : W1;
  const float* bias = blockIdx.y == 0 ? b0 : b1;
  short* Y        = blockIdx.y == 0 ? Y0 : Y1;

  const int tid = threadIdx.x;
  int x = blockIdx.x;
  int wg = (x & 7) * 128 + (x >> 3);       // XCD-chunked
  const int m0 = (wg >> 2) * 128;
  const int o0 = (wg & 3) * 128;
  const int b = m0 >> 12, t0 = m0 & 4095;  // 128-row tiles never straddle b
  const float* Xb = Xf + (size_t)b * CC * TT + t0;

  const int wid = tid >> 6, lane = tid & 63;
  const int wr = (wid >> 1) * 64, wc = (wid & 1) * 64;
  const int lr = lane & 15, g = lane >> 4;
  const int lk8 = g * 8;
  const int swz8 = (g ^ ((lr >> 1) & 3)) * 8;            // W read swizzle
  const int srow0 = tid >> 2;
  const int scol  = ((tid & 3) ^ ((tid >> 3) & 3)) * 8;  // W source swizzle

  const int t4 = (tid & 31) * 4;           // A staging coords
  const int c4 = (tid >> 5) * 4;

  f32x4 acc[4][4] = {};

  // prologue: A(0) -> Am[0]; issue W(0) gld16; issue A(1) -> rc
  {
    float4 r0[4];
    #pragma unroll
    for (int j = 0; j < 4; ++j)
      r0[j] = *(const float4*)(Xb + (size_t)(c4 + j) * TT + t4);
    #pragma unroll
    for (int jt = 0; jt < 4; ++jt) {
      int m = t4 + jt;
      s16x4 h = { f2b(r0[0][jt]), f2b(r0[1][jt]), f2b(r0[2][jt]), f2b(r0[3][jt]) };
      *(s16x4*)&Am[0][aadr(m, c4)] = h;
    }
  }
  #pragma unroll
  for (int it = 0; it < 2; ++it)
    gld16(&Ws[0][it * 2048 + tid * 8], W + (size_t)(o0 + it * 64 + srow0) * CC + scol);
  __builtin_amdgcn_sched_barrier(0);       // pin W(0) issue before A(1)
  float4 rc[4];
  #pragma unroll
  for (int j = 0; j < 4; ++j)
    rc[j] = *(const float4*)(Xb + (size_t)(32 + c4 + j) * TT + t4);

  for (int step = 0; step < 16; ++step) {
    const int cur = step & 1;
    // (1) issue W(s+1) gld16 FIRST (older than this step's A loads)
    if (step < 15) {
      const int k0 = (step + 1) * 32;
      #pragma unroll
      for (int it = 0; it < 2; ++it)
        gld16(&Ws[cur ^ 1][it * 2048 + tid * 8], W + (size_t)(o0 + it * 64 + srow0) * CC + k0 + scol);
    }
    __builtin_amdgcn_sched_barrier(0);
    // (2) issue A(s+2) register loads
    float4 rn[4];
    if (step < 14) {
      const int k2 = (step + 2) * 32;
      #pragma unroll
      for (int j = 0; j < 4; ++j)
        rn[j] = *(const float4*)(Xb + (size_t)(k2 + c4 + j) * TT + t4);
    }
    // (3) convert A(s+1) -> Am[cur^1]; data-dep wait on rc retires W(s) too
    if (step < 15) {
      #pragma unroll
      for (int jt = 0; jt < 4; ++jt) {
        int m = t4 + jt;
        s16x4 h = { f2b(rc[0][jt]), f2b(rc[1][jt]), f2b(rc[2][jt]), f2b(rc[3][jt]) };
        *(s16x4*)&Am[cur ^ 1][aadr(m, c4)] = h;
      }
    } else {
      asm volatile("s_waitcnt vmcnt(0)" ::: "memory");   // tail: W(15) landed
    }
    // (4) LDS writes visible + barrier (vmcnt NOT drained — prefetch lives)
    asm volatile("s_waitcnt lgkmcnt(0)" ::: "memory");
    __builtin_amdgcn_s_barrier();
    __builtin_amdgcn_sched_barrier(0);

    // (5) MFMA on current buffers
    bf16x8 af[4], bf[4];
    #pragma unroll
    for (int m = 0; m < 4; ++m) af[m] = *(const bf16x8*)&Am[cur][aadr(wr + m * 16 + lr, lk8)];
    #pragma unroll
    for (int n = 0; n < 4; ++n) bf[n] = *(const bf16x8*)&Ws[cur][(wc + n * 16 + lr) * 32 + swz8];
    #pragma unroll
    for (int m = 0; m < 4; ++m)
      #pragma unroll
      for (int n = 0; n < 4; ++n)
        acc[m][n] = __builtin_amdgcn_mfma_f32_16x16x32_bf16(af[m], bf[n], acc[m][n], 0, 0, 0);

    // (6) buffer-reuse barrier (LDS reads complete before next-step writes)
    __builtin_amdgcn_sched_barrier(0);
    __builtin_amdgcn_s_barrier();
    __builtin_amdgcn_sched_barrier(0);

    if (step < 14) {
      #pragma unroll
      for (int j = 0; j < 4; ++j) rc[j] = rn[j];
    }
  }

  const int lq4 = (lane >> 4) * 4;
  #pragma unroll
  for (int m = 0; m < 4; ++m)
    #pragma unroll
    for (int r = 0; r < 4; ++r) {
      size_t row = (size_t)(m0 + wr + m * 16 + lq4 + r) * CC;
      #pragma unroll
      for (int n = 0; n < 4; ++n) {
        int o = o0 + wc + n * 16 + lr;
        Y[row + o] = f2b(acc[m][n][r] + bias[o]);
      }
    }
}

// ---------------------------------------------------------------------------
// Row feature kernel on [row][512] bf16, wave per row, in-place; all 3
// tensors in one launch (blockIdx.y = mode).
// mode 0=Q (rms->elu+1->per-head softmax->*8^-0.5)
//      1=K (rms->elu+1->EXP, masked rows -> 0)   [normalization deferred]
//      2=V (rms->elu+1->/64)
// ---------------------------------------------------------------------------
__global__ __launch_bounds__(256) void feat_all(short* __restrict__ qf, short* __restrict__ kf,
                                                short* __restrict__ vf,
                                                const float* __restrict__ gq,
                                                const float* __restrict__ gk,
                                                const float* __restrict__ gv,
                                                const unsigned char* __restrict__ mask)
{
  const int mode = blockIdx.y;
  short* buf = mode == 0 ? qf : (mode == 1 ? kf : vf);
  const float* g = mode == 0 ? gq : (mode == 1 ? gk : gv);
  const int row = blockIdx.x * 4 + (threadIdx.x >> 6);
  const int lane = threadIdx.x & 63;
  short* p = buf + (size_t)row * CC + lane * 8;
  if (mode == 1 && mask[row]) {            // whole (b,t) row masked -> exp = 0
    bf16x8 z = { 0,0,0,0,0,0,0,0 };
    *(bf16x8*)p = z;
    return;
  }
  bf16x8 v = *(const bf16x8*)p;
  float x[8], ss = 0.f;
  #pragma unroll
  for (int j = 0; j < 8; ++j) { x[j] = b2f(v[j]); ss += x[j] * x[j]; }
  #pragma unroll
  for (int off = 32; off; off >>= 1) ss += __shfl_xor(ss, off);
  float rn = rsqrtf(ss * (1.0f / CC) + EPS);
  float4 g0 = *(const float4*)(g + lane * 8);
  float4 g1 = *(const float4*)(g + lane * 8 + 4);
  float gv8[8] = { g0.x, g0.y, g0.z, g0.w, g1.x, g1.y, g1.z, g1.w };
  float f[8];
  #pragma unroll
  for (int j = 0; j < 8; ++j) {
    float t = x[j] * rn * gv8[j];
    f[j] = t > 0.f ? t + 1.f : __expf(t);
  }
  bf16x8 o;
  if (mode == 1) {
    #pragma unroll
    for (int j = 0; j < 8; ++j) o[j] = f2b(__expf(f[j]));   // unnormalized exp
  } else if (mode == 2) {
    #pragma unroll
    for (int j = 0; j < 8; ++j) o[j] = f2b(f[j] * (1.0f / DH));
  } else {  // Q: softmax over head (64 c = 8 lanes), no max-sub (f <= ~24)
    float ls = 0.f;
    #pragma unroll
    for (int j = 0; j < 8; ++j) { f[j] = __expf(f[j]); ls += f[j]; }
    ls += __shfl_xor(ls, 1); ls += __shfl_xor(ls, 2); ls += __shfl_xor(ls, 4);
    float sc = 0.35355339059327373f / ls;     // 8^-0.5 / sum
    #pragma unroll
    for (int j = 0; j < 8; ++j) o[j] = f2b(f[j] * sc);
  }
  *(bf16x8*)p = o;
}

// column-sum of kf_exp over t: S[b][c] = sum_t kfe[b][t][c]
__global__ __launch_bounds__(256) void ksm_sum(const short* __restrict__ kfe,
                                               float* __restrict__ S)
{
  const int b = blockIdx.y, tch = blockIdx.x;
  const int c2 = threadIdx.x * 2;
  float s0 = 0.f, s1 = 0.f;
  for (int t = 0; t < 128; ++t) {
    unsigned u = *(const unsigned*)&kfe[((size_t)b * TT + tch * 128 + t) * CC + c2];
    s0 += __uint_as_float(u << 16);
    s1 += __uint_as_float(u & 0xffff0000u);
  }
  atomicAdd(&S[b * CC + c2], s0);
  atomicAdd(&S[b * CC + c2 + 1], s1);
}

// ---------------------------------------------------------------------------
// ctx partials from t-major kfe/vf: P[tc][bh][q][v] = sum_t kfe[t][q]*vf[t][v]
// ---------------------------------------------------------------------------
__global__ __launch_bounds__(256) void ctx_t(const short* __restrict__ kf,
                                             const short* __restrict__ vf,
                                             float* __restrict__ P)
{
  __shared__ short Ks[64 * 64];
  __shared__ short Vs[64 * 64];
  const int tc = blockIdx.x, bh = blockIdx.y;
  const int b = bh >> 3, h = bh & 7;
  const int tid = threadIdx.x, wid = tid >> 6, lane = tid & 63;
  const int lr = lane & 15, lg = lane >> 4;
  f32x4 acc[4] = {};

  for (int ts = 0; ts < 8; ++ts) {
    #pragma unroll
    for (int i = 0; i < 2; ++i) {
      int n = i * 256 + tid;
      int t = n >> 3, ch = (n & 7) * 8;
      size_t src = ((size_t)b * TT + tc * 512 + ts * 64 + t) * CC + h * DH + ch;
      gld16(Ks + n * 8, kf + src);
      gld16(Vs + n * 8, vf + src);
    }
    __syncthreads();
    #pragma unroll
    for (int kk = 0; kk < 64; kk += 32) {
      short a[8];
      #pragma unroll
      for (int j = 0; j < 8; ++j)
        a[j] = Ks[(kk + lg * 8 + j) * 64 + wid * 16 + lr];
      bf16x8 af = *(const bf16x8*)&a[0];
      #pragma unroll
      for (int n = 0; n < 4; ++n) {
        short bv[8];
        #pragma unroll
        for (int j = 0; j < 8; ++j)
          bv[j] = Vs[(kk + lg * 8 + j) * 64 + n * 16 + lr];
        acc[n] = __builtin_amdgcn_mfma_f32_16x16x32_bf16(af, *(const bf16x8*)&bv[0],
                                                         acc[n], 0, 0, 0);
      }
    }
    __syncthreads();
  }
  float* pp = P + ((size_t)tc * 64 + bh) * (DH * DH);
  const int lq4 = lg * 4;
  #pragma unroll
  for (int n = 0; n < 4; ++n)
    #pragma unroll
    for (int r = 0; r < 4; ++r)
      pp[(wid * 16 + lq4 + r) * DH + n * 16 + lr] = acc[n][r];
}

// reduce chunk partials, apply 1/S (deferred k-softmax norm), emit CT[bh][v][q]
__global__ __launch_bounds__(256) void ctx_reduce(const float* __restrict__ P,
                                                  const float* __restrict__ S,
                                                  short* __restrict__ CT)
{
  int i = blockIdx.x * 256 + threadIdx.x;    // (bh, q, v), v fastest
  float s = 0.f;
  #pragma unroll
  for (int c = 0; c < 8; ++c) s += P[(size_t)c * 64 * DH * DH + i];
  int bh = i >> 12, rem = i & 4095, q = rem >> 6, v = rem & 63;
  int b = bh >> 3, h = bh & 7;
  float inv = 1.f / S[b * CC + h * DH + q];
  CT[((size_t)bh << 12) + v * 64 + q] = f2b(s * inv);
}

// ---------------------------------------------------------------------------
// attn: ao[row][h*64+v] = sum_q qf[row][h*64+q] * CT[bh][v][q]
// ---------------------------------------------------------------------------
__global__ __launch_bounds__(256) void attn_t(const short* __restrict__ qf,
                                              const short* __restrict__ CT,
                                              short* __restrict__ ao)
{
  __shared__ short As[128 * 72];
  __shared__ short Cs[64 * 72];
  const int m0 = blockIdx.x * 128, h = blockIdx.y;
  const int tid = threadIdx.x, wid = tid >> 6, lane = tid & 63;
  const int lr = lane & 15, lk8 = (lane >> 4) * 8;

  #pragma unroll
  for (int i = 0; i < 4; ++i) {
    int n = i * 256 + tid;
    int r = n >> 3, ch = (n & 7) * 8;
    *(bf16x8*)&As[r * 72 + ch] =
        *(const bf16x8*)(qf + (size_t)(m0 + r) * CC + h * DH + ch);
  }
  {
    const int bh0 = (m0 / TT) * 8 + h;
    #pragma unroll
    for (int i = 0; i < 2; ++i) {
      int n = i * 256 + tid;
      int v = n >> 3, ch = (n & 7) * 8;
      *(bf16x8*)&Cs[v * 72 + ch] = *(const bf16x8*)(CT + ((size_t)bh0 << 12) + v * 64 + ch);
    }
  }
  __syncthreads();

  const int wr = wid * 32;
  f32x4 acc[2][4] = {};
  #pragma unroll
  for (int kk = 0; kk < 64; kk += 32) {
    bf16x8 af[2], cf[4];
    #pragma unroll
    for (int m = 0; m < 2; ++m) af[m] = *(const bf16x8*)&As[(wr + m * 16 + lr) * 72 + kk + lk8];
    #pragma unroll
    for (int n = 0; n < 4; ++n) cf[n] = *(const bf16x8*)&Cs[(n * 16 + lr) * 72 + kk + lk8];
    #pragma unroll
    for (int m = 0; m < 2; ++m)
      #pragma unroll
      for (int n = 0; n < 4; ++n)
        acc[m][n] = __builtin_amdgcn_mfma_f32_16x16x32_bf16(af[m], cf[n], acc[m][n], 0, 0, 0);
  }
  const int lq4 = (lane >> 4) * 4;
  #pragma unroll
  for (int m = 0; m < 2; ++m)
    #pragma unroll
    for (int r = 0; r < 4; ++r) {
      size_t row = (size_t)(m0 + wr + m * 16 + lq4 + r) * CC + h * DH;
      #pragma unroll
      for (int n = 0; n < 4; ++n)
        ao[row + n * 16 + lr] = f2b(acc[m][n][r]);
    }
}

// ---------------------------------------------------------------------------
// fused final v3 (r19 measured-best): 128-t x 512-c tile, 512 thr, 139 KB LDS.
// ---------------------------------------------------------------------------
#define ZSTR 136
__device__ __forceinline__ int zadr(int c, int t) {
  return c * ZSTR + ((c >> 7) & 3) * 8 + t;
}

__global__ __launch_bounds__(512) void final_fused(const short* __restrict__ pj,
                                                   const short* __restrict__ qt,
                                                   const float* __restrict__ g,
                                                   float* __restrict__ out)
{
  __shared__ short z[512 * ZSTR + 32];     // 139,328 B
  __shared__ float rmss[128];
  const int t0 = blockIdx.x * 128, b = blockIdx.y;
  const int tid = threadIdx.x;

  // pass 1: thread = (t = tid>>2 in 0..127, cb = (tid&3)*128)
  {
    const int t = tid >> 2, cb = (tid & 3) * 128;
    const size_t row = ((size_t)b * TT + t0 + t) * CC + cb;
    float ss = 0.f;
    #pragma unroll
    for (int j = 0; j < 16; ++j) {
      bf16x8 a = *(const bf16x8*)(pj + row + j * 8);
      bf16x8 q = *(const bf16x8*)(qt + row + j * 8);
      #pragma unroll
      for (int e = 0; e < 8; ++e) {
        float zf = b2f(a[e]) + b2f(q[e]);
        ss += zf * zf;
        z[zadr(cb + j * 8 + e, t)] = f2b(zf);
      }
    }
    ss += __shfl_xor(ss, 1);
    ss += __shfl_xor(ss, 2);
    if ((tid & 3) == 0) rmss[t] = rsqrtf(ss * (1.0f / CC) + EPS);
  }
  __syncthreads();

  // pass 2: 4 c-passes; thread = (c = p*128 + tid>>2, tcs = (tid&3)*32)
  const int ci = tid >> 2, tcs = (tid & 3) * 32;
  #pragma unroll 1
  for (int p = 0; p < 4; ++p) {
    const int cc = p * 128 + ci;
    const float gc = g[cc];
    float* dst = out + ((size_t)b * CC + cc) * TT + t0 + tcs;
    #pragma unroll
    for (int q8 = 0; q8 < 4; ++q8) {
      bf16x8 zv = *(const bf16x8*)&z[zadr(cc, tcs + q8 * 8)];
      float4 o0 = { b2f(zv[0]) * rmss[tcs+q8*8+0] * gc, b2f(zv[1]) * rmss[tcs+q8*8+1] * gc,
                    b2f(zv[2]) * rmss[tcs+q8*8+2] * gc, b2f(zv[3]) * rmss[tcs+q8*8+3] * gc };
      float4 o1 = { b2f(zv[4]) * rmss[tcs+q8*8+4] * gc, b2f(zv[5]) * rmss[tcs+q8*8+5] * gc,
                    b2f(zv[6]) * rmss[tcs+q8*8+6] * gc, b2f(zv[7]) * rmss[tcs+q8*8+7] * gc };
      *(float4*)(dst + q8 * 8) = o0;
      *(float4*)(dst + q8 * 8 + 4) = o1;
    }
  }
}

// ---------------------------------------------------------------------------
extern "C" void kernel_launch(void* const* d_in, const int* in_sizes, int n_in,
                              void* d_out, int out_size, void* d_ws, size_t ws_size,
                              hipStream_t stream) {
  (void)in_sizes; (void)n_in; (void)out_size; (void)ws_size;
  const float* queries = (const float*)d_in[0];
  const float* keys    = (const float*)d_in[1];
  const float* values  = (const float*)d_in[2];
  const unsigned char* mask = (const unsigned char*)d_in[3];
  const float* Wq = (const float*)d_in[4];
  const float* bq = (const float*)d_in[5];
  const float* gq = (const float*)d_in[6];
  const float* Wk = (const float*)d_in[7];
  const float* bk = (const float*)d_in[8];
  const float* gk = (const float*)d_in[9];
  const float* Wv = (const float*)d_in[10];
  const float* bv = (const float*)d_in[11];
  const float* gv = (const float*)d_in[12];
  const float* Wp = (const float*)d_in[13];
  const float* bp = (const float*)d_in[14];
  const float* g_out = (const float*)d_in[15];

  const size_t NCT = (size_t)NROWS * CC;       // 16,777,216 elements
  short* qt = (short*)d_ws;                    // bf16 [row][c] transposed queries
  short* qf = qt + NCT;                        // feature buffers
  short* kf = qf + NCT;
  short* vf = kf + NCT;
  short* ao = vf + NCT;                        // attention output
  short* pj = ao + NCT;                        // projection output
  float* ctxP = (float*)(pj + NCT);            // 8 x 64 x 4096 fp32
  short* CT  = (short*)(ctxP + (size_t)8 * 64 * DH * DH);   // [bh][v][q] bf16
  short* wqb = CT + (size_t)64 * DH * DH;
  short* wkb = wqb + (size_t)CC * CC;
  short* wvb = wkb + (size_t)CC * CC;
  short* wpb = wvb + (size_t)CC * CC;
  float* S   = (float*)(wpb + (size_t)CC * CC);   // [B][C] softmax sums

  hipMemsetAsync(S, 0, (size_t)BB * CC * sizeof(float), stream);

  conv_w4<<<dim3(CC * CC / 2048, 4), 256, 0, stream>>>(Wq, Wk, Wv, Wp, wqb, wkb, wvb, wpb);

  transpose_cvt1<<<dim3(TT / 256, CC / 64, BB), 256, 0, stream>>>(queries, qt);

  gemm_tc<<<dim3(1024), 256, 0, stream>>>(qt, wqb, bq, qf);

  gemm_direct2<<<dim3(1024, 2), 256, 0, stream>>>(keys, values, wkb, wvb,
                                                  bk, bv, kf, vf);

  feat_all<<<dim3(NROWS / 4, 3), 256, 0, stream>>>(qf, kf, vf, gq, gk, gv, mask);

  ksm_sum<<<dim3(32, BB), 256, 0, stream>>>(kf, S);

  ctx_t<<<dim3(8, BB * HH), 256, 0, stream>>>(kf, vf, ctxP);
  ctx_reduce<<<dim3(64 * DH * DH / 256), 256, 0, stream>>>(ctxP, S, CT);

  attn_t<<<dim3(NROWS / 128, HH), 256, 0, stream>>>(qf, CT, ao);

  gemm_tc<<<dim3(1024), 256, 0, stream>>>(ao, wpb, bp, pj);

  final_fused<<<dim3(TT / 128, BB), 512, 0, stream>>>(pj, qt, g_out, (float*)d_out);
}